// Round 7
// baseline (201.052 us; speedup 1.0000x reference)
//
#include <hip/hip_runtime.h>
#include <hip/hip_bf16.h>
#include <stdint.h>

// GRU cell, B=32768, IN=256, H=256, CONCAT=512. Fused bf16-MFMA kernel.
// R13 = MT=128 restructure, grid 256 = exactly 1 block/CU, single shot.
// Ledger: R9 intra-block pipelining neutral; R10 2x occupancy neutral/worse;
// R12 nt hints regression (WRITE_SIZE +10GB from unmerged partial lines) and
// falsified the L2-thrash theory (weight L2 BW 7 of 34 TB/s -- not bound).
// Remaining theory: ~2500 cyc of FIXED latency/sync overhead per barrier
// phase (measured 4100 cyc/phase vs ~1500 MFMA-busy), paid 12 phases x 2
// rounds. MT=128 doubles MFMA per phase (~3700 cyc) against the same fixed
// overhead, halves rounds (1 stage/prologue/drain instead of 2), halves
// weight L2 traffic (393->196 MB). LDS 128 KB (8-phase-template precedent).
// Registers: acc 192 + B 24 (per-ks, no dbuf: co-wave drift covers L2
// latency) + slab 16 + A ~8 + misc ~= 255; (512,2) caps 256. Biases loaded
// late to cut main-loop live regs. Spill detector: WRITE_SIZE >> 33 MB.

typedef float  f32x4  __attribute__((ext_vector_type(4)));
typedef __bf16 bf16x8 __attribute__((ext_vector_type(8)));
typedef short  s16x8  __attribute__((ext_vector_type(8)));

#define B_TOT   32768
#define MT      128
#define WRZ_ELEMS (512*512)

__device__ __forceinline__ unsigned short f2b(float f) {
    union { float f; unsigned int u; } v; v.f = f;
    unsigned int r = (v.u + 0x7FFFu + ((v.u >> 16) & 1u)) >> 16;  // RNE
    return (unsigned short)r;
}
__device__ __forceinline__ float b2f(unsigned short b) {
    union { unsigned int u; float f; } v; v.u = ((unsigned int)b) << 16;
    return v.f;
}
__device__ __forceinline__ ushort2 pk2(float a, float b) {   // v_cvt_pk_bf16_f32
    __hip_bfloat162 t = __float22bfloat162_rn(make_float2(a, b));
    union { __hip_bfloat162 h; ushort2 u; } c; c.h = t; return c.u;
}
__device__ __forceinline__ float sigmoid_f(float x) {
    return 1.0f / (1.0f + __expf(-x));
}
__device__ __forceinline__ float tanh_f(float x) {
    return 1.0f - 2.0f / (__expf(2.0f * x) + 1.0f);
}

// bf16 LDS tile 128x512 (128 KB), XOR-swizzled at 16B (8-elem) granularity.
__device__ __forceinline__ int lds_idx(int row, int col) {
    return row * 512 + ((((col >> 3) ^ (row & 7)) << 3) | (col & 7));
}

// 8 fp32 (2x f32x4) -> 8 bf16 -> one 16B LDS write.
__device__ __forceinline__ void stash8(unsigned short* dst, f32x4 a, f32x4 b) {
    union { ushort2 u2[4]; s16x8 v; } pk;
    pk.u2[0] = pk2(a[0], a[1]); pk.u2[1] = pk2(a[2], a[3]);
    pk.u2[2] = pk2(b[0], b[1]); pk.u2[3] = pk2(b[2], b[3]);
    *reinterpret_cast<s16x8*>(dst) = pk.v;
}

// ---------------------------------------------------------------------------
// Prep (unchanged): fp32 -> bf16 ks-major per-wave fragment pages.
// wrz page (wave w): [ks 0..15][jn 0..3][512]; jn 0,1 r-cols, jn 2,3 z-cols.
// wg  page (wave w): [ks 0..15][j 0..1][512]; k<256 whx, k>=256 whh.
// ---------------------------------------------------------------------------
__global__ void prep_weights(const float* __restrict__ wr,
                             const float* __restrict__ wz,
                             const float* __restrict__ whh,
                             const float* __restrict__ whx,
                             unsigned short* __restrict__ wrz,
                             unsigned short* __restrict__ wg) {
    const int b = blockIdx.x;
    const int t = threadIdx.x;
    union { s16x8 v; unsigned short u[8]; } tmp;

    if (b < 128) {                       // wrz: block = (w, ks)
        int w = b >> 4, ks = b & 15;
        int jn = t >> 6, l = t & 63;
        int kbase = ks * 32 + ((l >> 4) << 3);
        int n = 32 * w + ((jn & 1) << 4) + (l & 15);
        const float* src = (jn < 2) ? wr : wz;
        #pragma unroll
        for (int jj = 0; jj < 8; ++jj)
            tmp.u[jj] = f2b(src[(kbase + jj) * 256 + n]);
        *reinterpret_cast<s16x8*>(wrz + (size_t)w * 32768 + ks * 2048 + t * 8) = tmp.v;
    } else {                             // wg: block = (w, ks-pair)
        int b2 = b - 128;
        int w = b2 >> 3, ksp = b2 & 7;
        int ksl = t >> 7, j = (t >> 6) & 1, l = t & 63;
        int ks = ksp * 2 + ksl;
        int kbase = ks * 32 + ((l >> 4) << 3);
        int n = 32 * w + (j << 4) + (l & 15);
        #pragma unroll
        for (int jj = 0; jj < 8; ++jj) {
            int k = kbase + jj;
            tmp.u[jj] = f2b((k < 256) ? whx[k * 256 + n] : whh[(k - 256) * 256 + n]);
        }
        *reinterpret_cast<s16x8*>(wg + (size_t)w * 16384 + ksp * 2048 + t * 8) = tmp.v;
    }
}

// ---------------------------------------------------------------------------
// Fused GRU: 512 threads (8 waves), 128 rows/block, grid 256 (1 block/CU).
// Wave w owns r/z/g cols [32w,32w+32) over 128 rows (mt 0..7).
// Slab pipeline: phase p MFMAs slab p (k in [64p,64p+64)) while loading
// slab p+1 to regs; stash+barrier at phase end. B frags loaded per-ks
// (co-resident wave covers L2 latency). Gates: a=sigmoid(r+br)*h ->
// x-region; h stashed in r-acc. Tail: g += a @ whh. Epilogue blend.
// ---------------------------------------------------------------------------
__global__ __launch_bounds__(512, 2)
void gru_fused(const float* __restrict__ x, const float* __restrict__ h,
               const unsigned short* __restrict__ wrz,
               const unsigned short* __restrict__ wg,
               const float* __restrict__ br, const float* __restrict__ bz,
               const float* __restrict__ bh, float* __restrict__ out) {
    __shared__ unsigned short xcA[128 * 512];   // 128 KB

    const int tid  = threadIdx.x;
    const int lane = tid & 63;
    const int wv   = __builtin_amdgcn_readfirstlane(tid >> 6);  // wave 0..7
    const int m0   = lane & 15;
    const int q    = lane >> 4;
    const int rowBase = blockIdx.x * MT;

    // ---- Stage geometry: thread t = row (t>>2), float cols (t&3)*16..+16
    // of each 128x64 slab: 4 f32x4 loads -> 2 stash8 (16B swizzled writes).
    const int srow = tid >> 2;          // 0..127
    const int sc16 = (tid & 3) << 4;    // 0,16,32,48
    const float* xrow = x + (size_t)(rowBase + srow) * 256 + sc16;
    const float* hrow = h + (size_t)(rowBase + srow) * 256 + sc16;

    const unsigned short* wrzP = wrz + (size_t)wv * 32768;
    const unsigned short* wgP  = wg  + (size_t)wv * 16384;

    // ---- Stage slab 0 (x cols 0..63)
    {
        const f32x4* p = reinterpret_cast<const f32x4*>(xrow);
        f32x4 a0 = p[0], a1 = p[1], a2 = p[2], a3 = p[3];
        stash8(&xcA[lds_idx(srow, sc16)],     a0, a1);
        stash8(&xcA[lds_idx(srow, sc16 + 8)], a2, a3);
    }
    __syncthreads();

    f32x4 rz[4][8];     // jn 0,1 = r; jn 2,3 = z   (128 regs)
    f32x4 gac[2][8];    //                          (64 regs)
    #pragma unroll
    for (int jn = 0; jn < 4; ++jn)
        #pragma unroll
        for (int mt = 0; mt < 8; ++mt)
            rz[jn][mt] = (f32x4){0.f, 0.f, 0.f, 0.f};
    #pragma unroll
    for (int j = 0; j < 2; ++j)
        #pragma unroll
        for (int mt = 0; mt < 8; ++mt)
            gac[j][mt] = (f32x4){0.f, 0.f, 0.f, 0.f};

    // ---- Main loop: 8 phases x 2 ks. Phase p: issue slab p+1 loads, MFMA
    // slab p (B frags per-ks), stash slab p+1, lgkmcnt(0)+barrier (vmcnt
    // NOT drained -- slab loads fly under the MFMA block).
    f32x4 S0, S1, S2, S3;
    #pragma unroll
    for (int grp = 0; grp < 8; ++grp) {
        if (grp < 7) {
            const int s = grp + 1;
            const f32x4* p = reinterpret_cast<const f32x4*>(
                (s < 4) ? (xrow + 64 * s) : (hrow + 64 * (s - 4)));
            S0 = p[0]; S1 = p[1]; S2 = p[2]; S3 = p[3];
        }
        __builtin_amdgcn_sched_barrier(0);   // slab loads stay above MFMAs
        #pragma unroll
        for (int k2 = 0; k2 < 2; ++k2) {
            const int ks = grp * 2 + k2;
            s16x8 Bf[4];
            #pragma unroll
            for (int jn = 0; jn < 4; ++jn)
                Bf[jn] = *reinterpret_cast<const s16x8*>(
                    wrzP + ks * 2048 + jn * 512 + lane * 8);
            s16x8 Bg[2];
            if (ks < 8) {
                #pragma unroll
                for (int j = 0; j < 2; ++j)
                    Bg[j] = *reinterpret_cast<const s16x8*>(
                        wgP + ks * 1024 + j * 512 + lane * 8);
            }
            #pragma unroll
            for (int mt = 0; mt < 8; ++mt) {
                const int row = mt * 16 + m0;
                const int idx = row * 512 + ((((ks << 2) | q) ^ (row & 7)) << 3);
                bf16x8 afr = __builtin_bit_cast(bf16x8,
                    *reinterpret_cast<const s16x8*>(&xcA[idx]));
                #pragma unroll
                for (int jn = 0; jn < 4; ++jn)
                    rz[jn][mt] = __builtin_amdgcn_mfma_f32_16x16x32_bf16(
                        afr, __builtin_bit_cast(bf16x8, Bf[jn]), rz[jn][mt], 0, 0, 0);
                if (ks < 8) {
                    #pragma unroll
                    for (int j = 0; j < 2; ++j)
                        gac[j][mt] = __builtin_amdgcn_mfma_f32_16x16x32_bf16(
                            afr, __builtin_bit_cast(bf16x8, Bg[j]), gac[j][mt], 0, 0, 0);
                }
            }
        }
        __builtin_amdgcn_sched_barrier(0);   // keep slab stash below MFMAs
        if (grp < 7) {
            const int s = grp + 1;
            stash8(&xcA[lds_idx(srow, 64 * s + sc16)],     S0, S1);
            stash8(&xcA[lds_idx(srow, 64 * s + sc16 + 8)], S2, S3);
            asm volatile("s_waitcnt lgkmcnt(0)" ::: "memory");
            __builtin_amdgcn_sched_barrier(0);
            __builtin_amdgcn_s_barrier();
            __builtin_amdgcn_sched_barrier(0);
        }
    }
    __syncthreads();   // all LDS A-reads done before x-region overwrite

    // ---- Gates: a = sigmoid(r+br)*h -> LDS x-region; stash h in r-acc
    {
        float brv[2];
        #pragma unroll
        for (int j = 0; j < 2; ++j) brv[j] = br[32 * wv + j * 16 + m0];
        #pragma unroll
        for (int j = 0; j < 2; ++j) {
            int col = 32 * wv + j * 16 + m0;
            #pragma unroll
            for (int mt = 0; mt < 8; ++mt) {
                #pragma unroll
                for (int rg = 0; rg < 4; ++rg) {
                    int row = mt * 16 + q * 4 + rg;
                    float hval = b2f(xcA[lds_idx(row, 256 + col)]);
                    float rs = sigmoid_f(rz[j][mt][rg] + brv[j]);
                    xcA[lds_idx(row, col)] = f2b(rs * hval);
                    rz[j][mt][rg] = hval;
                }
            }
        }
    }
    __syncthreads();   // a visible to all waves

    // ---- Tail: g += a @ whh, kt 0..7 (wg pages 8..15), per-kt B loads
    #pragma unroll
    for (int kt = 0; kt < 8; ++kt) {
        s16x8 Tb[2];
        #pragma unroll
        for (int j = 0; j < 2; ++j)
            Tb[j] = *reinterpret_cast<const s16x8*>(
                wgP + (8 + kt) * 1024 + j * 512 + lane * 8);
        #pragma unroll
        for (int mt = 0; mt < 8; ++mt) {
            const int row = mt * 16 + m0;
            const int idx = row * 512 + ((((kt << 2) | q) ^ (row & 7)) << 3);
            bf16x8 afr = __builtin_bit_cast(bf16x8,
                *reinterpret_cast<const s16x8*>(&xcA[idx]));
            #pragma unroll
            for (int j = 0; j < 2; ++j)
                gac[j][mt] = __builtin_amdgcn_mfma_f32_16x16x32_bf16(
                    afr, __builtin_bit_cast(bf16x8, Tb[j]), gac[j][mt], 0, 0, 0);
        }
    }

    // ---- Epilogue: h_out = h + z*(tanh(g+bh) - h)
    {
        float bzv[2], bhv[2];
        #pragma unroll
        for (int j = 0; j < 2; ++j) {
            int col = 32 * wv + j * 16 + m0;
            bzv[j] = bz[col]; bhv[j] = bh[col];
        }
        #pragma unroll
        for (int j = 0; j < 2; ++j) {
            int col = 32 * wv + j * 16 + m0;
            #pragma unroll
            for (int mt = 0; mt < 8; ++mt) {
                #pragma unroll
                for (int rg = 0; rg < 4; ++rg) {
                    int row = mt * 16 + q * 4 + rg;
                    float zs = sigmoid_f(rz[2 + j][mt][rg] + bzv[j]);
                    float gv = tanh_f(gac[j][mt][rg] + bhv[j]);
                    float hval = rz[j][mt][rg];
                    out[(size_t)(rowBase + row) * 256 + col] = hval + zs * (gv - hval);
                }
            }
        }
    }
}

extern "C" void kernel_launch(void* const* d_in, const int* in_sizes, int n_in,
                              void* d_out, int out_size, void* d_ws, size_t ws_size,
                              hipStream_t stream) {
    const float* x   = (const float*)d_in[0];
    const float* h   = (const float*)d_in[1];
    const float* wr  = (const float*)d_in[2];
    const float* wz  = (const float*)d_in[3];
    const float* whh = (const float*)d_in[4];
    const float* whx = (const float*)d_in[5];
    const float* br  = (const float*)d_in[6];
    const float* bz  = (const float*)d_in[7];
    const float* bh  = (const float*)d_in[8];
    float* out = (float*)d_out;

    unsigned short* wrz = (unsigned short*)d_ws;       // 512 KB
    unsigned short* wg  = wrz + WRZ_ELEMS;             // 256 KB

    prep_weights<<<192, 256, 0, stream>>>(wr, wz, whh, whx, wrz, wg);
    gru_fused<<<B_TOT / MT, 512, 0, stream>>>(x, h, wrz, wg, br, bz, bh, out);
}

// Round 8
// 185.939 us; speedup vs baseline: 1.0813x; 1.0813x over previous
//
#include <hip/hip_runtime.h>
#include <hip/hip_bf16.h>
#include <stdint.h>

// GRU cell, B=32768, IN=256, H=256, CONCAT=512. Fused bf16-MFMA kernel.
// R14 = persistent 2-tile blocks + cheap-transcendental epilogue.
// Ledger: R9 pipelining neutral; R10 occupancy neutral; R12 nt regression;
// R13 MT=128 spilled (WRITE 165 GB). Static model says ~10-15us, measured
// ~55us/pass -- stall-dominated, unlocalized. This round removes the two
// remaining unattacked costs: (1) the serial relaunch between the two grid
// passes: grid 256 (1 block/CU), each block runs TWO MT=64 row-tiles;
// tile-1's slab-0/1 loads + group-0 B-frags issue during tile-0's
// gates/tail/epilogue (~2000cyc cover), and tile-1's weight reads hit the
// now-warm same-XCD L2. (2) IEEE-divide sigmoid/tanh (no -ffast-math =>
// ~10-op divides) -> v_rcp_f32 (1 ulp, invisible under bf16 tolerance);
// gates f2b (4 ALU each) -> paired HW cvt_pk. Per-tile machinery = R9.

typedef float  f32x4  __attribute__((ext_vector_type(4)));
typedef __bf16 bf16x8 __attribute__((ext_vector_type(8)));
typedef short  s16x8  __attribute__((ext_vector_type(8)));

#define B_TOT   32768
#define MT      64
#define WRZ_ELEMS (512*512)

__device__ __forceinline__ unsigned short f2b(float f) {
    union { float f; unsigned int u; } v; v.f = f;
    unsigned int r = (v.u + 0x7FFFu + ((v.u >> 16) & 1u)) >> 16;  // RNE
    return (unsigned short)r;
}
__device__ __forceinline__ float b2f(unsigned short b) {
    union { unsigned int u; float f; } v; v.u = ((unsigned int)b) << 16;
    return v.f;
}
__device__ __forceinline__ ushort2 pk2(float a, float b) {   // v_cvt_pk_bf16_f32
    __hip_bfloat162 t = __float22bfloat162_rn(make_float2(a, b));
    union { __hip_bfloat162 h; ushort2 u; } c; c.h = t; return c.u;
}
// rcp-based gates: v_rcp_f32 is ~1 ulp; error invisible vs bf16 rounding.
__device__ __forceinline__ float sigmoid_f(float x) {
    return __builtin_amdgcn_rcpf(1.0f + __expf(-x));
}
__device__ __forceinline__ float tanh_f(float x) {
    return 1.0f - 2.0f * __builtin_amdgcn_rcpf(__expf(2.0f * x) + 1.0f);
}

// bf16 LDS tile 64x512 (64 KB), XOR-swizzled at 16B (8-elem) granularity.
__device__ __forceinline__ int lds_idx(int row, int col) {
    return row * 512 + ((((col >> 3) ^ (row & 7)) << 3) | (col & 7));
}

// 8 fp32 (2x f32x4) -> 8 bf16 -> one 16B LDS write (stage slab stash).
__device__ __forceinline__ void stash8(unsigned short* dst, f32x4 a, f32x4 b) {
    union { ushort2 u2[4]; s16x8 v; } pk;
    pk.u2[0] = pk2(a[0], a[1]); pk.u2[1] = pk2(a[2], a[3]);
    pk.u2[2] = pk2(b[0], b[1]); pk.u2[3] = pk2(b[2], b[3]);
    *reinterpret_cast<s16x8*>(dst) = pk.v;
}
__device__ __forceinline__ f32x4 ld4(const float* p) {
    return *reinterpret_cast<const f32x4*>(p);
}

// ---------------------------------------------------------------------------
// Prep (unchanged): fp32 -> bf16 ks-major per-wave fragment pages.
// wrz page (wave w): [ks 0..15][jn 0..3][512]; jn 0,1 r-cols, jn 2,3 z-cols.
// wg  page (wave w): [ks 0..15][j 0..1][512]; k<256 whx, k>=256 whh.
// ---------------------------------------------------------------------------
__global__ void prep_weights(const float* __restrict__ wr,
                             const float* __restrict__ wz,
                             const float* __restrict__ whh,
                             const float* __restrict__ whx,
                             unsigned short* __restrict__ wrz,
                             unsigned short* __restrict__ wg) {
    const int b = blockIdx.x;
    const int t = threadIdx.x;
    union { s16x8 v; unsigned short u[8]; } tmp;

    if (b < 128) {                       // wrz: block = (w, ks)
        int w = b >> 4, ks = b & 15;
        int jn = t >> 6, l = t & 63;
        int kbase = ks * 32 + ((l >> 4) << 3);
        int n = 32 * w + ((jn & 1) << 4) + (l & 15);
        const float* src = (jn < 2) ? wr : wz;
        #pragma unroll
        for (int jj = 0; jj < 8; ++jj)
            tmp.u[jj] = f2b(src[(kbase + jj) * 256 + n]);
        *reinterpret_cast<s16x8*>(wrz + (size_t)w * 32768 + ks * 2048 + t * 8) = tmp.v;
    } else {                             // wg: block = (w, ks-pair)
        int b2 = b - 128;
        int w = b2 >> 3, ksp = b2 & 7;
        int ksl = t >> 7, j = (t >> 6) & 1, l = t & 63;
        int ks = ksp * 2 + ksl;
        int kbase = ks * 32 + ((l >> 4) << 3);
        int n = 32 * w + (j << 4) + (l & 15);
        #pragma unroll
        for (int jj = 0; jj < 8; ++jj) {
            int k = kbase + jj;
            tmp.u[jj] = f2b((k < 256) ? whx[k * 256 + n] : whh[(k - 256) * 256 + n]);
        }
        *reinterpret_cast<s16x8*>(wg + (size_t)w * 16384 + ksp * 2048 + t * 8) = tmp.v;
    }
}

// ---------------------------------------------------------------------------
// Fused GRU: 512 threads (8 waves), grid 256 (1 block/CU), 2 row-tiles of
// 64 rows per block. Wave w owns r/z/g cols [32w,32w+32).
// Per tile: slab-pipelined stage + 8 MFMA phases (R9), gates, tail, epi.
// Cross-tile: tile-1 slab0/1 + B group0 loads issue during tile-0
// gates/tail/epi; barrier protects LDS before tile-1 stash.
// ---------------------------------------------------------------------------
__global__ __launch_bounds__(512, 2)
void gru_fused(const float* __restrict__ x, const float* __restrict__ h,
               const unsigned short* __restrict__ wrz,
               const unsigned short* __restrict__ wg,
               const float* __restrict__ br, const float* __restrict__ bz,
               const float* __restrict__ bh, float* __restrict__ out) {
    __shared__ unsigned short xcA[64 * 512];   // 64 KB

    const int tid  = threadIdx.x;
    const int lane = tid & 63;
    const int wv   = tid >> 6;          // wave 0..7
    const int m0   = lane & 15;
    const int q    = lane >> 4;

    float brv[2], bzv[2], bhv[2];
    #pragma unroll
    for (int j = 0; j < 2; ++j) {
        int col = 32 * wv + j * 16 + m0;
        brv[j] = br[col]; bzv[j] = bz[col]; bhv[j] = bh[col];
    }

    // ---- Slab staging geometry: slab s = 64 rows x 64 k.
    const int srow  = tid >> 3;
    const int scol8 = (tid & 7) << 3;
    // Tile 0 base pointers; tile 1 = +64 rows = +16384 floats.
    const float* xrow0 = x + (size_t)(blockIdx.x * 2 * MT + srow) * 256 + scol8;
    const float* hrow0 = h + (size_t)(blockIdx.x * 2 * MT + srow) * 256 + scol8;

    const unsigned short* wrzP = wrz + (size_t)wv * 32768;
    const unsigned short* wgP  = wg  + (size_t)wv * 16384;

    // ---- Preamble: issue tile-0 slab 0,1 loads; preload B group 0.
    f32x4 Sa[2], Sb[2];
    Sa[0] = ld4(xrow0);       Sb[0] = ld4(xrow0 + 4);
    Sa[1] = ld4(xrow0 + 64);  Sb[1] = ld4(xrow0 + 68);

    s16x8 Bb[2][12];
    #pragma unroll
    for (int k2 = 0; k2 < 2; ++k2) {
        #pragma unroll
        for (int jn = 0; jn < 4; ++jn)
            Bb[0][k2 * 6 + jn] = *reinterpret_cast<const s16x8*>(
                wrzP + k2 * 2048 + jn * 512 + lane * 8);
        #pragma unroll
        for (int j = 0; j < 2; ++j)
            Bb[0][k2 * 6 + 4 + j] = *reinterpret_cast<const s16x8*>(
                wgP + k2 * 1024 + j * 512 + lane * 8);
    }

    #pragma unroll
    for (int tile = 0; tile < 2; ++tile) {
        const int rowBase = blockIdx.x * 2 * MT + tile * MT;
        const float* xrow = xrow0 + tile * 16384;
        const float* hrow = hrow0 + tile * 16384;

        // ---- Stage entry: Sa/Sb hold this tile's slab0/1; stash slab0.
        stash8(&xcA[lds_idx(srow, scol8)], Sa[0], Sb[0]);
        asm volatile("s_waitcnt lgkmcnt(0)" ::: "memory");
        __builtin_amdgcn_sched_barrier(0);
        __builtin_amdgcn_s_barrier();
        __builtin_amdgcn_sched_barrier(0);

        f32x4 rz[4][4];     // jn 0,1 = r; jn 2,3 = z
        f32x4 gac[2][4];
        #pragma unroll
        for (int jn = 0; jn < 4; ++jn)
            #pragma unroll
            for (int mt = 0; mt < 4; ++mt)
                rz[jn][mt] = (f32x4){0.f, 0.f, 0.f, 0.f};
        #pragma unroll
        for (int j = 0; j < 2; ++j)
            #pragma unroll
            for (int mt = 0; mt < 4; ++mt)
                gac[j][mt] = (f32x4){0.f, 0.f, 0.f, 0.f};

        // ---- Main loop: 8 phases x 2 ks (R9 slab pipeline).
        #pragma unroll
        for (int grp = 0; grp < 8; ++grp) {
            const int cur = grp & 1, nxt = cur ^ 1;
            if (grp < 6) {
                const int s = grp + 2;
                const float* p = (s < 4) ? (xrow + 64 * s) : (hrow + 64 * (s - 4));
                Sa[grp & 1] = ld4(p); Sb[grp & 1] = ld4(p + 4);
            }
            if (grp < 7) {
                int gn = grp + 1;
                #pragma unroll
                for (int k2 = 0; k2 < 2; ++k2) {
                    int ks = gn * 2 + k2;
                    #pragma unroll
                    for (int jn = 0; jn < 4; ++jn)
                        Bb[nxt][k2 * 6 + jn] = *reinterpret_cast<const s16x8*>(
                            wrzP + ks * 2048 + jn * 512 + lane * 8);
                    if (gn < 4) {
                        #pragma unroll
                        for (int j = 0; j < 2; ++j)
                            Bb[nxt][k2 * 6 + 4 + j] = *reinterpret_cast<const s16x8*>(
                                wgP + ks * 1024 + j * 512 + lane * 8);
                    }
                }
            }
            __builtin_amdgcn_sched_barrier(0);   // loads above, MFMAs below
            #pragma unroll
            for (int k2 = 0; k2 < 2; ++k2) {
                int ks = grp * 2 + k2;
                bf16x8 afr[4];
                #pragma unroll
                for (int mt = 0; mt < 4; ++mt) {
                    int row = mt * 16 + m0;
                    int idx = row * 512 + ((((ks << 2) | q) ^ (row & 7)) << 3);
                    afr[mt] = __builtin_bit_cast(bf16x8,
                        *reinterpret_cast<const s16x8*>(&xcA[idx]));
                }
                #pragma unroll
                for (int jn = 0; jn < 4; ++jn) {
                    bf16x8 bf = __builtin_bit_cast(bf16x8, Bb[cur][k2 * 6 + jn]);
                    #pragma unroll
                    for (int mt = 0; mt < 4; ++mt)
                        rz[jn][mt] = __builtin_amdgcn_mfma_f32_16x16x32_bf16(
                            afr[mt], bf, rz[jn][mt], 0, 0, 0);
                }
                if (grp < 4) {
                    #pragma unroll
                    for (int j = 0; j < 2; ++j) {
                        bf16x8 bf = __builtin_bit_cast(bf16x8, Bb[cur][k2 * 6 + 4 + j]);
                        #pragma unroll
                        for (int mt = 0; mt < 4; ++mt)
                            gac[j][mt] = __builtin_amdgcn_mfma_f32_16x16x32_bf16(
                                afr[mt], bf, gac[j][mt], 0, 0, 0);
                    }
                }
            }
            __builtin_amdgcn_sched_barrier(0);   // slab write below MFMAs
            if (grp < 7) {
                const int sb = (grp + 1) & 1;
                stash8(&xcA[lds_idx(srow, 64 * (grp + 1) + scol8)], Sa[sb], Sb[sb]);
                asm volatile("s_waitcnt lgkmcnt(0)" ::: "memory");
                __builtin_amdgcn_sched_barrier(0);
                __builtin_amdgcn_s_barrier();
                __builtin_amdgcn_sched_barrier(0);
            }
        }
        __syncthreads();   // all LDS A-reads done before x-region overwrite

        // ---- Preload tail group 0 (whh pages 8,9)
        s16x8 Tb[2][4];
        #pragma unroll
        for (int k2 = 0; k2 < 2; ++k2)
            #pragma unroll
            for (int j = 0; j < 2; ++j)
                Tb[0][k2 * 2 + j] = *reinterpret_cast<const s16x8*>(
                    wgP + (8 + k2) * 1024 + j * 512 + lane * 8);

        // ---- Cross-tile prefetch: issue tile-1 slab0/1 + B group0 loads
        // now; they fly under gates+tail+epilogue (~2000 cyc).
        if (tile == 0) {
            const float* xn = xrow0 + 16384;
            Sa[0] = ld4(xn);      Sb[0] = ld4(xn + 4);
            Sa[1] = ld4(xn + 64); Sb[1] = ld4(xn + 68);
            #pragma unroll
            for (int k2 = 0; k2 < 2; ++k2) {
                #pragma unroll
                for (int jn = 0; jn < 4; ++jn)
                    Bb[0][k2 * 6 + jn] = *reinterpret_cast<const s16x8*>(
                        wrzP + k2 * 2048 + jn * 512 + lane * 8);
                #pragma unroll
                for (int j = 0; j < 2; ++j)
                    Bb[0][k2 * 6 + 4 + j] = *reinterpret_cast<const s16x8*>(
                        wgP + k2 * 1024 + j * 512 + lane * 8);
            }
        }

        // ---- Gates: a = sigmoid(r+br)*h -> LDS x-region (paired HW cvt);
        // stash h in r-acc.
        #pragma unroll
        for (int j = 0; j < 2; ++j) {
            int col = 32 * wv + j * 16 + m0;
            #pragma unroll
            for (int mt = 0; mt < 4; ++mt) {
                #pragma unroll
                for (int rg = 0; rg < 4; rg += 2) {
                    int row0 = mt * 16 + q * 4 + rg;
                    int row1 = row0 + 1;
                    float h0 = b2f(xcA[lds_idx(row0, 256 + col)]);
                    float h1 = b2f(xcA[lds_idx(row1, 256 + col)]);
                    float a0 = sigmoid_f(rz[j][mt][rg]     + brv[j]) * h0;
                    float a1 = sigmoid_f(rz[j][mt][rg + 1] + brv[j]) * h1;
                    ushort2 c = pk2(a0, a1);
                    xcA[lds_idx(row0, col)] = c.x;
                    xcA[lds_idx(row1, col)] = c.y;
                    rz[j][mt][rg]     = h0;
                    rz[j][mt][rg + 1] = h1;
                }
            }
        }
        __syncthreads();   // a visible to all waves

        // ---- Tail: g += a @ whh, 4 groups x 2 kt, double-buffered
        #pragma unroll
        for (int tg = 0; tg < 4; ++tg) {
            const int cur = tg & 1, nxt = cur ^ 1;
            if (tg < 3) {
                #pragma unroll
                for (int k2 = 0; k2 < 2; ++k2)
                    #pragma unroll
                    for (int j = 0; j < 2; ++j)
                        Tb[nxt][k2 * 2 + j] = *reinterpret_cast<const s16x8*>(
                            wgP + (10 + tg * 2 + k2) * 1024 + j * 512 + lane * 8);
            }
            __builtin_amdgcn_sched_barrier(0);
            #pragma unroll
            for (int k2 = 0; k2 < 2; ++k2) {
                int kt = tg * 2 + k2;
                bf16x8 afr[4];
                #pragma unroll
                for (int mt = 0; mt < 4; ++mt) {
                    int row = mt * 16 + m0;
                    int idx = row * 512 + ((((kt << 2) | q) ^ (row & 7)) << 3);
                    afr[mt] = __builtin_bit_cast(bf16x8,
                        *reinterpret_cast<const s16x8*>(&xcA[idx]));
                }
                #pragma unroll
                for (int j = 0; j < 2; ++j) {
                    bf16x8 bf = __builtin_bit_cast(bf16x8, Tb[cur][k2 * 2 + j]);
                    #pragma unroll
                    for (int mt = 0; mt < 4; ++mt)
                        gac[j][mt] = __builtin_amdgcn_mfma_f32_16x16x32_bf16(
                            afr[mt], bf, gac[j][mt], 0, 0, 0);
                }
            }
        }

        // ---- Epilogue: h_out = h + z*(tanh(g+bh) - h)
        #pragma unroll
        for (int j = 0; j < 2; ++j) {
            int col = 32 * wv + j * 16 + m0;
            #pragma unroll
            for (int mt = 0; mt < 4; ++mt) {
                #pragma unroll
                for (int rg = 0; rg < 4; ++rg) {
                    int row = mt * 16 + q * 4 + rg;
                    float zs = sigmoid_f(rz[2 + j][mt][rg] + bzv[j]);
                    float gv = tanh_f(gac[j][mt][rg] + bhv[j]);
                    float hval = rz[j][mt][rg];
                    out[(size_t)(rowBase + row) * 256 + col] = hval + zs * (gv - hval);
                }
            }
        }

        if (tile == 0)
            __syncthreads();   // all tail LDS reads done before tile-1 stash
    }
}

extern "C" void kernel_launch(void* const* d_in, const int* in_sizes, int n_in,
                              void* d_out, int out_size, void* d_ws, size_t ws_size,
                              hipStream_t stream) {
    const float* x   = (const float*)d_in[0];
    const float* h   = (const float*)d_in[1];
    const float* wr  = (const float*)d_in[2];
    const float* wz  = (const float*)d_in[3];
    const float* whh = (const float*)d_in[4];
    const float* whx = (const float*)d_in[5];
    const float* br  = (const float*)d_in[6];
    const float* bz  = (const float*)d_in[7];
    const float* bh  = (const float*)d_in[8];
    float* out = (float*)d_out;

    unsigned short* wrz = (unsigned short*)d_ws;       // 512 KB
    unsigned short* wg  = wrz + WRZ_ELEMS;             // 256 KB

    prep_weights<<<192, 256, 0, stream>>>(wr, wz, whh, whx, wrz, wg);
    gru_fused<<<B_TOT / (2 * MT), 512, 0, stream>>>(x, h, wrz, wg, br, bz, bh, out);
}

// Round 11
// 143.424 us; speedup vs baseline: 1.4018x; 1.2964x over previous
//
#include <hip/hip_runtime.h>
#include <hip/hip_bf16.h>
#include <stdint.h>

// GRU cell, B=32768, IN=256, H=256, CONCAT=512. Fused bf16-MFMA kernel.
// R15 = R9 (best verified structure: slab-pipelined MT=64, (512,2), hot
// ~55us) + the VALU trims that rode along with R14's spill and never got
// a clean read: (1) sigmoid/tanh via v_rcp_f32 instead of IEEE divide
// (no -ffast-math => ~10-op divide sequence; 64 gate evals/thread);
// (2) gates' bf16 stores via paired v_cvt_pk_bf16_f32 instead of 32
// scalar 4-op f2b. No structural change, no new cross-section live
// ranges (R13/R14 lesson: register budget is saturated -- any added
// live range spills; WRITE_SIZE is the spill detector, expect ~33 MB).
// (3rd submit: rounds 9/10 died on container acquisition, not the kernel;
// same infra signature as round 1, which passed clean on resubmit.)

typedef float  f32x4  __attribute__((ext_vector_type(4)));
typedef __bf16 bf16x8 __attribute__((ext_vector_type(8)));
typedef short  s16x8  __attribute__((ext_vector_type(8)));

#define B_TOT   32768
#define MT      64
#define WRZ_ELEMS (512*512)

__device__ __forceinline__ unsigned short f2b(float f) {
    union { float f; unsigned int u; } v; v.f = f;
    unsigned int r = (v.u + 0x7FFFu + ((v.u >> 16) & 1u)) >> 16;  // RNE
    return (unsigned short)r;
}
__device__ __forceinline__ float b2f(unsigned short b) {
    union { unsigned int u; float f; } v; v.u = ((unsigned int)b) << 16;
    return v.f;
}
__device__ __forceinline__ ushort2 pk2(float a, float b) {   // v_cvt_pk_bf16_f32
    __hip_bfloat162 t = __float22bfloat162_rn(make_float2(a, b));
    union { __hip_bfloat162 h; ushort2 u; } c; c.h = t; return c.u;
}
// rcp-based gates: v_rcp_f32 is ~1 ulp; error invisible vs bf16 rounding.
__device__ __forceinline__ float sigmoid_f(float x) {
    return __builtin_amdgcn_rcpf(1.0f + __expf(-x));
}
__device__ __forceinline__ float tanh_f(float x) {
    return 1.0f - 2.0f * __builtin_amdgcn_rcpf(__expf(2.0f * x) + 1.0f);
}

// bf16 LDS tile 64x512 (64 KB), XOR-swizzled at 16B (8-elem) granularity.
__device__ __forceinline__ int lds_idx(int row, int col) {
    return row * 512 + ((((col >> 3) ^ (row & 7)) << 3) | (col & 7));
}

// 8 fp32 (2x f32x4) -> 8 bf16 -> one 16B LDS write (stage slab stash).
__device__ __forceinline__ void stash8(unsigned short* dst, f32x4 a, f32x4 b) {
    union { ushort2 u2[4]; s16x8 v; } pk;
    pk.u2[0] = pk2(a[0], a[1]); pk.u2[1] = pk2(a[2], a[3]);
    pk.u2[2] = pk2(b[0], b[1]); pk.u2[3] = pk2(b[2], b[3]);
    *reinterpret_cast<s16x8*>(dst) = pk.v;
}
__device__ __forceinline__ f32x4 ld4(const float* p) {
    return *reinterpret_cast<const f32x4*>(p);
}

// ---------------------------------------------------------------------------
// Prep (unchanged): fp32 -> bf16 ks-major per-wave fragment pages.
// wrz page (wave w): [ks 0..15][jn 0..3][512]; jn 0,1 r-cols, jn 2,3 z-cols.
// wg  page (wave w): [ks 0..15][j 0..1][512]; k<256 whx, k>=256 whh.
// ---------------------------------------------------------------------------
__global__ void prep_weights(const float* __restrict__ wr,
                             const float* __restrict__ wz,
                             const float* __restrict__ whh,
                             const float* __restrict__ whx,
                             unsigned short* __restrict__ wrz,
                             unsigned short* __restrict__ wg) {
    const int b = blockIdx.x;
    const int t = threadIdx.x;
    union { s16x8 v; unsigned short u[8]; } tmp;

    if (b < 128) {                       // wrz: block = (w, ks)
        int w = b >> 4, ks = b & 15;
        int jn = t >> 6, l = t & 63;
        int kbase = ks * 32 + ((l >> 4) << 3);
        int n = 32 * w + ((jn & 1) << 4) + (l & 15);
        const float* src = (jn < 2) ? wr : wz;
        #pragma unroll
        for (int jj = 0; jj < 8; ++jj)
            tmp.u[jj] = f2b(src[(kbase + jj) * 256 + n]);
        *reinterpret_cast<s16x8*>(wrz + (size_t)w * 32768 + ks * 2048 + t * 8) = tmp.v;
    } else {                             // wg: block = (w, ks-pair)
        int b2 = b - 128;
        int w = b2 >> 3, ksp = b2 & 7;
        int ksl = t >> 7, j = (t >> 6) & 1, l = t & 63;
        int ks = ksp * 2 + ksl;
        int kbase = ks * 32 + ((l >> 4) << 3);
        int n = 32 * w + (j << 4) + (l & 15);
        #pragma unroll
        for (int jj = 0; jj < 8; ++jj) {
            int k = kbase + jj;
            tmp.u[jj] = f2b((k < 256) ? whx[k * 256 + n] : whh[(k - 256) * 256 + n]);
        }
        *reinterpret_cast<s16x8*>(wg + (size_t)w * 16384 + ksp * 2048 + t * 8) = tmp.v;
    }
}

// ---------------------------------------------------------------------------
// Fused GRU: 512 threads (8 waves), 64 rows/block, grid 512.
// Wave w owns r/z/g cols [32w,32w+32). Slab-pipelined stage + 8 MFMA phases.
// Gates: a=sigmoid(r+br)*h -> x-region; h stashed in r-acc.
// Tail: 4 groups of 2 kt. Epilogue: h + z*(tanh(g+bh)-h).
// ---------------------------------------------------------------------------
__global__ __launch_bounds__(512, 2)
void gru_fused(const float* __restrict__ x, const float* __restrict__ h,
               const unsigned short* __restrict__ wrz,
               const unsigned short* __restrict__ wg,
               const float* __restrict__ br, const float* __restrict__ bz,
               const float* __restrict__ bh, float* __restrict__ out) {
    __shared__ unsigned short xcA[64 * 512];   // 64 KB

    const int tid  = threadIdx.x;
    const int lane = tid & 63;
    const int wv   = tid >> 6;          // wave 0..7
    const int m0   = lane & 15;
    const int q    = lane >> 4;
    const int rowBase = blockIdx.x * MT;

    float brv[2], bzv[2], bhv[2];
    #pragma unroll
    for (int j = 0; j < 2; ++j) {
        int col = 32 * wv + j * 16 + m0;
        brv[j] = br[col]; bzv[j] = bz[col]; bhv[j] = bh[col];
    }

    // ---- Slab staging geometry: slab s = 64 rows x 64 k (k in [64s,64s+64)).
    // Thread t stages row (t>>3), float cols [ (t&7)*8 .. +8 ) of each slab:
    // 2 f32x4 loads -> 4 pk2 -> one 16B swizzled LDS write.
    const int srow  = tid >> 3;
    const int scol8 = (tid & 7) << 3;
    const float* xrow = x + (size_t)(rowBase + srow) * 256 + scol8;
    const float* hrow = h + (size_t)(rowBase + srow) * 256 + scol8;

    const unsigned short* wrzP = wrz + (size_t)wv * 32768;
    const unsigned short* wgP  = wg  + (size_t)wv * 16384;

    // ---- Preamble: issue slab 0,1 loads; preload B group 0; write slab 0.
    f32x4 Sa[2], Sb[2];
    {
        Sa[0] = ld4(xrow);       Sb[0] = ld4(xrow + 4);        // slab 0
        Sa[1] = ld4(xrow + 64);  Sb[1] = ld4(xrow + 68);       // slab 1
    }

    s16x8 Bb[2][12];
    #pragma unroll
    for (int k2 = 0; k2 < 2; ++k2) {
        #pragma unroll
        for (int jn = 0; jn < 4; ++jn)
            Bb[0][k2 * 6 + jn] = *reinterpret_cast<const s16x8*>(
                wrzP + k2 * 2048 + jn * 512 + lane * 8);
        #pragma unroll
        for (int j = 0; j < 2; ++j)
            Bb[0][k2 * 6 + 4 + j] = *reinterpret_cast<const s16x8*>(
                wgP + k2 * 1024 + j * 512 + lane * 8);
    }

    stash8(&xcA[lds_idx(srow, scol8)], Sa[0], Sb[0]);   // slab 0
    asm volatile("s_waitcnt lgkmcnt(0)" ::: "memory");
    __builtin_amdgcn_sched_barrier(0);
    __builtin_amdgcn_s_barrier();
    __builtin_amdgcn_sched_barrier(0);

    f32x4 rz[4][4];     // jn 0,1 = r; jn 2,3 = z
    f32x4 gac[2][4];
    #pragma unroll
    for (int jn = 0; jn < 4; ++jn)
        #pragma unroll
        for (int mt = 0; mt < 4; ++mt)
            rz[jn][mt] = (f32x4){0.f, 0.f, 0.f, 0.f};
    #pragma unroll
    for (int j = 0; j < 2; ++j)
        #pragma unroll
        for (int mt = 0; mt < 4; ++mt)
            gac[j][mt] = (f32x4){0.f, 0.f, 0.f, 0.f};

    // ---- Main loop: 8 phases. Phase p: issue slab p+2 loads, prefetch B
    // group p+1, MFMA group p (reads slab p), write slab p+1, raw barrier
    // (lgkmcnt only -- stage/B loads stay in flight across the barrier).
    #pragma unroll
    for (int grp = 0; grp < 8; ++grp) {
        const int cur = grp & 1, nxt = cur ^ 1;
        // Stage loads: slab grp+2 -> reg buffer (grp&1)
        if (grp < 6) {
            const int s = grp + 2;
            const float* p = (s < 4) ? (xrow + 64 * s) : (hrow + 64 * (s - 4));
            Sa[grp & 1] = ld4(p); Sb[grp & 1] = ld4(p + 4);
        }
        // Prefetch next group's B fragments
        if (grp < 7) {
            int gn = grp + 1;
            #pragma unroll
            for (int k2 = 0; k2 < 2; ++k2) {
                int ks = gn * 2 + k2;
                #pragma unroll
                for (int jn = 0; jn < 4; ++jn)
                    Bb[nxt][k2 * 6 + jn] = *reinterpret_cast<const s16x8*>(
                        wrzP + ks * 2048 + jn * 512 + lane * 8);
                if (gn < 4) {
                    #pragma unroll
                    for (int j = 0; j < 2; ++j)
                        Bb[nxt][k2 * 6 + 4 + j] = *reinterpret_cast<const s16x8*>(
                            wgP + ks * 1024 + j * 512 + lane * 8);
                }
            }
        }
        __builtin_amdgcn_sched_barrier(0);   // loads stay above, MFMAs below
        #pragma unroll
        for (int k2 = 0; k2 < 2; ++k2) {
            int ks = grp * 2 + k2;
            bf16x8 afr[4];
            #pragma unroll
            for (int mt = 0; mt < 4; ++mt) {
                int row = mt * 16 + m0;
                int idx = row * 512 + ((((ks << 2) | q) ^ (row & 7)) << 3);
                afr[mt] = __builtin_bit_cast(bf16x8,
                    *reinterpret_cast<const s16x8*>(&xcA[idx]));
            }
            #pragma unroll
            for (int jn = 0; jn < 4; ++jn) {
                bf16x8 bf = __builtin_bit_cast(bf16x8, Bb[cur][k2 * 6 + jn]);
                #pragma unroll
                for (int mt = 0; mt < 4; ++mt)
                    rz[jn][mt] = __builtin_amdgcn_mfma_f32_16x16x32_bf16(
                        afr[mt], bf, rz[jn][mt], 0, 0, 0);
            }
            if (grp < 4) {
                #pragma unroll
                for (int j = 0; j < 2; ++j) {
                    bf16x8 bf = __builtin_bit_cast(bf16x8, Bb[cur][k2 * 6 + 4 + j]);
                    #pragma unroll
                    for (int mt = 0; mt < 4; ++mt)
                        gac[j][mt] = __builtin_amdgcn_mfma_f32_16x16x32_bf16(
                            afr[mt], bf, gac[j][mt], 0, 0, 0);
                }
            }
        }
        __builtin_amdgcn_sched_barrier(0);   // keep slab write below MFMAs
        // Write slab grp+1 (loaded last phase) and phase-barrier.
        if (grp < 7) {
            const int sb = (grp + 1) & 1;
            stash8(&xcA[lds_idx(srow, 64 * (grp + 1) + scol8)], Sa[sb], Sb[sb]);
            asm volatile("s_waitcnt lgkmcnt(0)" ::: "memory");
            __builtin_amdgcn_sched_barrier(0);
            __builtin_amdgcn_s_barrier();
            __builtin_amdgcn_sched_barrier(0);
        }
    }
    __syncthreads();   // all LDS A-reads done before x-region overwrite

    // ---- Preload tail group 0 (whh pages 8,9) — gates VALU hides latency
    s16x8 Tb[2][4];
    #pragma unroll
    for (int k2 = 0; k2 < 2; ++k2)
        #pragma unroll
        for (int j = 0; j < 2; ++j)
            Tb[0][k2 * 2 + j] = *reinterpret_cast<const s16x8*>(
                wgP + (8 + k2) * 1024 + j * 512 + lane * 8);

    // ---- Gates: a = sigmoid(r+br)*h -> LDS x-region (paired HW cvt);
    // stash h in r-acc.
    #pragma unroll
    for (int j = 0; j < 2; ++j) {
        int col = 32 * wv + j * 16 + m0;
        #pragma unroll
        for (int mt = 0; mt < 4; ++mt) {
            #pragma unroll
            for (int rg = 0; rg < 4; rg += 2) {
                int row0 = mt * 16 + q * 4 + rg;
                int row1 = row0 + 1;
                float h0 = b2f(xcA[lds_idx(row0, 256 + col)]);
                float h1 = b2f(xcA[lds_idx(row1, 256 + col)]);
                float a0 = sigmoid_f(rz[j][mt][rg]     + brv[j]) * h0;
                float a1 = sigmoid_f(rz[j][mt][rg + 1] + brv[j]) * h1;
                ushort2 c = pk2(a0, a1);
                xcA[lds_idx(row0, col)] = c.x;
                xcA[lds_idx(row1, col)] = c.y;
                rz[j][mt][rg]     = h0;
                rz[j][mt][rg + 1] = h1;
            }
        }
    }
    __syncthreads();   // a visible to all waves

    // ---- Tail: g += a @ whh, 4 groups x 2 kt, double-buffered + fenced
    #pragma unroll
    for (int tg = 0; tg < 4; ++tg) {
        const int cur = tg & 1, nxt = cur ^ 1;
        if (tg < 3) {
            #pragma unroll
            for (int k2 = 0; k2 < 2; ++k2)
                #pragma unroll
                for (int j = 0; j < 2; ++j)
                    Tb[nxt][k2 * 2 + j] = *reinterpret_cast<const s16x8*>(
                        wgP + (10 + tg * 2 + k2) * 1024 + j * 512 + lane * 8);
        }
        __builtin_amdgcn_sched_barrier(0);
        #pragma unroll
        for (int k2 = 0; k2 < 2; ++k2) {
            int kt = tg * 2 + k2;
            bf16x8 afr[4];
            #pragma unroll
            for (int mt = 0; mt < 4; ++mt) {
                int row = mt * 16 + m0;
                int idx = row * 512 + ((((kt << 2) | q) ^ (row & 7)) << 3);
                afr[mt] = __builtin_bit_cast(bf16x8,
                    *reinterpret_cast<const s16x8*>(&xcA[idx]));
            }
            #pragma unroll
            for (int j = 0; j < 2; ++j) {
                bf16x8 bf = __builtin_bit_cast(bf16x8, Tb[cur][k2 * 2 + j]);
                #pragma unroll
                for (int mt = 0; mt < 4; ++mt)
                    gac[j][mt] = __builtin_amdgcn_mfma_f32_16x16x32_bf16(
                        afr[mt], bf, gac[j][mt], 0, 0, 0);
            }
        }
    }

    // ---- Epilogue: h_out = h + z*(tanh(g+bh) - h)
    #pragma unroll
    for (int j = 0; j < 2; ++j) {
        int col = 32 * wv + j * 16 + m0;
        #pragma unroll
        for (int mt = 0; mt < 4; ++mt) {
            #pragma unroll
            for (int rg = 0; rg < 4; ++rg) {
                int row = mt * 16 + q * 4 + rg;
                float zs = sigmoid_f(rz[2 + j][mt][rg] + bzv[j]);
                float gv = tanh_f(gac[j][mt][rg] + bhv[j]);
                float hval = rz[j][mt][rg];
                out[(size_t)(rowBase + row) * 256 + col] = hval + zs * (gv - hval);
            }
        }
    }
}

extern "C" void kernel_launch(void* const* d_in, const int* in_sizes, int n_in,
                              void* d_out, int out_size, void* d_ws, size_t ws_size,
                              hipStream_t stream) {
    const float* x   = (const float*)d_in[0];
    const float* h   = (const float*)d_in[1];
    const float* wr  = (const float*)d_in[2];
    const float* wz  = (const float*)d_in[3];
    const float* whh = (const float*)d_in[4];
    const float* whx = (const float*)d_in[5];
    const float* br  = (const float*)d_in[6];
    const float* bz  = (const float*)d_in[7];
    const float* bh  = (const float*)d_in[8];
    float* out = (float*)d_out;

    unsigned short* wrz = (unsigned short*)d_ws;       // 512 KB
    unsigned short* wg  = wrz + WRZ_ELEMS;             // 256 KB

    prep_weights<<<192, 256, 0, stream>>>(wr, wz, whh, whx, wrz, wg);
    gru_fused<<<B_TOT / MT, 512, 0, stream>>>(x, h, wrz, wg, br, bz, bh, out);
}

// Round 12
// 141.903 us; speedup vs baseline: 1.4168x; 1.0107x over previous
//
#include <hip/hip_runtime.h>
#include <hip/hip_bf16.h>
#include <stdint.h>

// GRU cell, B=32768, IN=256, H=256, CONCAT=512. Fused bf16-MFMA kernel.
// R16 = R15 (confirmed win: rcp gates + pk2, hot ~49us) with the barrier
// cadence HALVED: two A-slabs staged per phase, so in-loop barriers drop
// 7 -> 3. Tests R13's fixed-per-phase-overhead theory cleanly (R13 itself
// spilled). Register delta is ZERO: the old scheme also kept 2 slabs in
// flight (Sa/Sb[2], 16 regs); only the stash/barrier points move. B-frag
// double-buffer keeps its per-2-ks rhythm (register-private, no barrier
// dependency). MFMA order bit-identical -> absmax 0.03125 unchanged.
// Spill detector stays WRITE_SIZE (~36 MB expected).

typedef float  f32x4  __attribute__((ext_vector_type(4)));
typedef __bf16 bf16x8 __attribute__((ext_vector_type(8)));
typedef short  s16x8  __attribute__((ext_vector_type(8)));

#define B_TOT   32768
#define MT      64
#define WRZ_ELEMS (512*512)

__device__ __forceinline__ unsigned short f2b(float f) {
    union { float f; unsigned int u; } v; v.f = f;
    unsigned int r = (v.u + 0x7FFFu + ((v.u >> 16) & 1u)) >> 16;  // RNE
    return (unsigned short)r;
}
__device__ __forceinline__ float b2f(unsigned short b) {
    union { unsigned int u; float f; } v; v.u = ((unsigned int)b) << 16;
    return v.f;
}
__device__ __forceinline__ ushort2 pk2(float a, float b) {   // v_cvt_pk_bf16_f32
    __hip_bfloat162 t = __float22bfloat162_rn(make_float2(a, b));
    union { __hip_bfloat162 h; ushort2 u; } c; c.h = t; return c.u;
}
// rcp-based gates: v_rcp_f32 is ~1 ulp; error invisible vs bf16 rounding.
__device__ __forceinline__ float sigmoid_f(float x) {
    return __builtin_amdgcn_rcpf(1.0f + __expf(-x));
}
__device__ __forceinline__ float tanh_f(float x) {
    return 1.0f - 2.0f * __builtin_amdgcn_rcpf(__expf(2.0f * x) + 1.0f);
}

// bf16 LDS tile 64x512 (64 KB), XOR-swizzled at 16B (8-elem) granularity.
__device__ __forceinline__ int lds_idx(int row, int col) {
    return row * 512 + ((((col >> 3) ^ (row & 7)) << 3) | (col & 7));
}

// 8 fp32 (2x f32x4) -> 8 bf16 -> one 16B LDS write (stage slab stash).
__device__ __forceinline__ void stash8(unsigned short* dst, f32x4 a, f32x4 b) {
    union { ushort2 u2[4]; s16x8 v; } pk;
    pk.u2[0] = pk2(a[0], a[1]); pk.u2[1] = pk2(a[2], a[3]);
    pk.u2[2] = pk2(b[0], b[1]); pk.u2[3] = pk2(b[2], b[3]);
    *reinterpret_cast<s16x8*>(dst) = pk.v;
}
__device__ __forceinline__ f32x4 ld4(const float* p) {
    return *reinterpret_cast<const f32x4*>(p);
}

// ---------------------------------------------------------------------------
// Prep (unchanged): fp32 -> bf16 ks-major per-wave fragment pages.
// wrz page (wave w): [ks 0..15][jn 0..3][512]; jn 0,1 r-cols, jn 2,3 z-cols.
// wg  page (wave w): [ks 0..15][j 0..1][512]; k<256 whx, k>=256 whh.
// ---------------------------------------------------------------------------
__global__ void prep_weights(const float* __restrict__ wr,
                             const float* __restrict__ wz,
                             const float* __restrict__ whh,
                             const float* __restrict__ whx,
                             unsigned short* __restrict__ wrz,
                             unsigned short* __restrict__ wg) {
    const int b = blockIdx.x;
    const int t = threadIdx.x;
    union { s16x8 v; unsigned short u[8]; } tmp;

    if (b < 128) {                       // wrz: block = (w, ks)
        int w = b >> 4, ks = b & 15;
        int jn = t >> 6, l = t & 63;
        int kbase = ks * 32 + ((l >> 4) << 3);
        int n = 32 * w + ((jn & 1) << 4) + (l & 15);
        const float* src = (jn < 2) ? wr : wz;
        #pragma unroll
        for (int jj = 0; jj < 8; ++jj)
            tmp.u[jj] = f2b(src[(kbase + jj) * 256 + n]);
        *reinterpret_cast<s16x8*>(wrz + (size_t)w * 32768 + ks * 2048 + t * 8) = tmp.v;
    } else {                             // wg: block = (w, ks-pair)
        int b2 = b - 128;
        int w = b2 >> 3, ksp = b2 & 7;
        int ksl = t >> 7, j = (t >> 6) & 1, l = t & 63;
        int ks = ksp * 2 + ksl;
        int kbase = ks * 32 + ((l >> 4) << 3);
        int n = 32 * w + (j << 4) + (l & 15);
        #pragma unroll
        for (int jj = 0; jj < 8; ++jj) {
            int k = kbase + jj;
            tmp.u[jj] = f2b((k < 256) ? whx[k * 256 + n] : whh[(k - 256) * 256 + n]);
        }
        *reinterpret_cast<s16x8*>(wg + (size_t)w * 16384 + ksp * 2048 + t * 8) = tmp.v;
    }
}

// ---------------------------------------------------------------------------
// Fused GRU: 512 threads (8 waves), 64 rows/block, grid 512.
// Wave w owns r/z/g cols [32w,32w+32). 4 barrier-phases x 4 ks (2 slabs
// staged per phase); B frags double-buffered per 2-ks half-phase.
// Gates: a=sigmoid(r+br)*h -> x-region; h stashed in r-acc.
// Tail: 4 groups of 2 kt. Epilogue: h + z*(tanh(g+bh)-h).
// ---------------------------------------------------------------------------
__global__ __launch_bounds__(512, 2)
void gru_fused(const float* __restrict__ x, const float* __restrict__ h,
               const unsigned short* __restrict__ wrz,
               const unsigned short* __restrict__ wg,
               const float* __restrict__ br, const float* __restrict__ bz,
               const float* __restrict__ bh, float* __restrict__ out) {
    __shared__ unsigned short xcA[64 * 512];   // 64 KB

    const int tid  = threadIdx.x;
    const int lane = tid & 63;
    const int wv   = tid >> 6;          // wave 0..7
    const int m0   = lane & 15;
    const int q    = lane >> 4;
    const int rowBase = blockIdx.x * MT;

    float brv[2], bzv[2], bhv[2];
    #pragma unroll
    for (int j = 0; j < 2; ++j) {
        int col = 32 * wv + j * 16 + m0;
        brv[j] = br[col]; bzv[j] = bz[col]; bhv[j] = bh[col];
    }

    // ---- Slab staging geometry: slab s = 64 rows x 64 k (k in [64s,64s+64)).
    // Thread t stages row (t>>3), float cols [ (t&7)*8 .. +8 ) of each slab:
    // 2 f32x4 loads -> 4 pk2 -> one 16B swizzled LDS write.
    const int srow  = tid >> 3;
    const int scol8 = (tid & 7) << 3;
    const float* xrow = x + (size_t)(rowBase + srow) * 256 + scol8;
    const float* hrow = h + (size_t)(rowBase + srow) * 256 + scol8;

    const unsigned short* wrzP = wrz + (size_t)wv * 32768;
    const unsigned short* wgP  = wg  + (size_t)wv * 16384;

    // ---- Preamble: load slabs 0,1; preload B group 0; stash both slabs.
    f32x4 Sa[2], Sb[2];
    {
        Sa[0] = ld4(xrow);       Sb[0] = ld4(xrow + 4);        // slab 0
        Sa[1] = ld4(xrow + 64);  Sb[1] = ld4(xrow + 68);       // slab 1
    }

    s16x8 Bb[2][12];
    #pragma unroll
    for (int k2 = 0; k2 < 2; ++k2) {
        #pragma unroll
        for (int jn = 0; jn < 4; ++jn)
            Bb[0][k2 * 6 + jn] = *reinterpret_cast<const s16x8*>(
                wrzP + k2 * 2048 + jn * 512 + lane * 8);
        #pragma unroll
        for (int j = 0; j < 2; ++j)
            Bb[0][k2 * 6 + 4 + j] = *reinterpret_cast<const s16x8*>(
                wgP + k2 * 1024 + j * 512 + lane * 8);
    }

    stash8(&xcA[lds_idx(srow, scol8)],      Sa[0], Sb[0]);   // slab 0
    stash8(&xcA[lds_idx(srow, 64 + scol8)], Sa[1], Sb[1]);   // slab 1
    asm volatile("s_waitcnt lgkmcnt(0)" ::: "memory");
    __builtin_amdgcn_sched_barrier(0);
    __builtin_amdgcn_s_barrier();
    __builtin_amdgcn_sched_barrier(0);

    f32x4 rz[4][4];     // jn 0,1 = r; jn 2,3 = z
    f32x4 gac[2][4];
    #pragma unroll
    for (int jn = 0; jn < 4; ++jn)
        #pragma unroll
        for (int mt = 0; mt < 4; ++mt)
            rz[jn][mt] = (f32x4){0.f, 0.f, 0.f, 0.f};
    #pragma unroll
    for (int j = 0; j < 2; ++j)
        #pragma unroll
        for (int mt = 0; mt < 4; ++mt)
            gac[j][mt] = (f32x4){0.f, 0.f, 0.f, 0.f};

    // ---- Main loop: 8 groups of 2 ks; barrier-phase = 2 groups (4 ks).
    // Even grp: issue loads for slabs grp+2, grp+3 (held in regs).
    // Every grp: prefetch B group grp+1 (register dbuf, no barrier needed).
    // Odd grp end: stash slabs grp+1, grp+2; lgkmcnt(0)+s_barrier (vmcnt
    // NOT drained -- stage/B loads stay in flight across the barrier).
    #pragma unroll
    for (int grp = 0; grp < 8; ++grp) {
        const int cur = grp & 1, nxt = cur ^ 1;
        // Stage loads: slabs grp+2, grp+3 at even grp.
        if ((grp & 1) == 0 && grp < 6) {
            #pragma unroll
            for (int k = 0; k < 2; ++k) {
                const int s = grp + 2 + k;
                const float* p = (s < 4) ? (xrow + 64 * s) : (hrow + 64 * (s - 4));
                Sa[k] = ld4(p); Sb[k] = ld4(p + 4);
            }
        }
        // Prefetch next group's B fragments
        if (grp < 7) {
            int gn = grp + 1;
            #pragma unroll
            for (int k2 = 0; k2 < 2; ++k2) {
                int ks = gn * 2 + k2;
                #pragma unroll
                for (int jn = 0; jn < 4; ++jn)
                    Bb[nxt][k2 * 6 + jn] = *reinterpret_cast<const s16x8*>(
                        wrzP + ks * 2048 + jn * 512 + lane * 8);
                if (gn < 4) {
                    #pragma unroll
                    for (int j = 0; j < 2; ++j)
                        Bb[nxt][k2 * 6 + 4 + j] = *reinterpret_cast<const s16x8*>(
                            wgP + ks * 1024 + j * 512 + lane * 8);
                }
            }
        }
        __builtin_amdgcn_sched_barrier(0);   // loads stay above, MFMAs below
        #pragma unroll
        for (int k2 = 0; k2 < 2; ++k2) {
            int ks = grp * 2 + k2;
            bf16x8 afr[4];
            #pragma unroll
            for (int mt = 0; mt < 4; ++mt) {
                int row = mt * 16 + m0;
                int idx = row * 512 + ((((ks << 2) | q) ^ (row & 7)) << 3);
                afr[mt] = __builtin_bit_cast(bf16x8,
                    *reinterpret_cast<const s16x8*>(&xcA[idx]));
            }
            #pragma unroll
            for (int jn = 0; jn < 4; ++jn) {
                bf16x8 bf = __builtin_bit_cast(bf16x8, Bb[cur][k2 * 6 + jn]);
                #pragma unroll
                for (int mt = 0; mt < 4; ++mt)
                    rz[jn][mt] = __builtin_amdgcn_mfma_f32_16x16x32_bf16(
                        afr[mt], bf, rz[jn][mt], 0, 0, 0);
            }
            if (grp < 4) {
                #pragma unroll
                for (int j = 0; j < 2; ++j) {
                    bf16x8 bf = __builtin_bit_cast(bf16x8, Bb[cur][k2 * 6 + 4 + j]);
                    #pragma unroll
                    for (int mt = 0; mt < 4; ++mt)
                        gac[j][mt] = __builtin_amdgcn_mfma_f32_16x16x32_bf16(
                            afr[mt], bf, gac[j][mt], 0, 0, 0);
                }
            }
        }
        __builtin_amdgcn_sched_barrier(0);   // keep slab writes below MFMAs
        // Odd grp end: stash both pending slabs and phase-barrier.
        if ((grp & 1) == 1 && grp < 7) {
            #pragma unroll
            for (int k = 0; k < 2; ++k) {
                const int s = grp + 1 + k;
                stash8(&xcA[lds_idx(srow, 64 * s + scol8)], Sa[k], Sb[k]);
            }
            asm volatile("s_waitcnt lgkmcnt(0)" ::: "memory");
            __builtin_amdgcn_sched_barrier(0);
            __builtin_amdgcn_s_barrier();
            __builtin_amdgcn_sched_barrier(0);
        }
    }
    __syncthreads();   // all LDS A-reads done before x-region overwrite

    // ---- Preload tail group 0 (whh pages 8,9) — gates VALU hides latency
    s16x8 Tb[2][4];
    #pragma unroll
    for (int k2 = 0; k2 < 2; ++k2)
        #pragma unroll
        for (int j = 0; j < 2; ++j)
            Tb[0][k2 * 2 + j] = *reinterpret_cast<const s16x8*>(
                wgP + (8 + k2) * 1024 + j * 512 + lane * 8);

    // ---- Gates: a = sigmoid(r+br)*h -> LDS x-region (paired HW cvt);
    // stash h in r-acc.
    #pragma unroll
    for (int j = 0; j < 2; ++j) {
        int col = 32 * wv + j * 16 + m0;
        #pragma unroll
        for (int mt = 0; mt < 4; ++mt) {
            #pragma unroll
            for (int rg = 0; rg < 4; rg += 2) {
                int row0 = mt * 16 + q * 4 + rg;
                int row1 = row0 + 1;
                float h0 = b2f(xcA[lds_idx(row0, 256 + col)]);
                float h1 = b2f(xcA[lds_idx(row1, 256 + col)]);
                float a0 = sigmoid_f(rz[j][mt][rg]     + brv[j]) * h0;
                float a1 = sigmoid_f(rz[j][mt][rg + 1] + brv[j]) * h1;
                ushort2 c = pk2(a0, a1);
                xcA[lds_idx(row0, col)] = c.x;
                xcA[lds_idx(row1, col)] = c.y;
                rz[j][mt][rg]     = h0;
                rz[j][mt][rg + 1] = h1;
            }
        }
    }
    __syncthreads();   // a visible to all waves

    // ---- Tail: g += a @ whh, 4 groups x 2 kt, double-buffered + fenced
    #pragma unroll
    for (int tg = 0; tg < 4; ++tg) {
        const int cur = tg & 1, nxt = cur ^ 1;
        if (tg < 3) {
            #pragma unroll
            for (int k2 = 0; k2 < 2; ++k2)
                #pragma unroll
                for (int j = 0; j < 2; ++j)
                    Tb[nxt][k2 * 2 + j] = *reinterpret_cast<const s16x8*>(
                        wgP + (10 + tg * 2 + k2) * 1024 + j * 512 + lane * 8);
        }
        __builtin_amdgcn_sched_barrier(0);
        #pragma unroll
        for (int k2 = 0; k2 < 2; ++k2) {
            int kt = tg * 2 + k2;
            bf16x8 afr[4];
            #pragma unroll
            for (int mt = 0; mt < 4; ++mt) {
                int row = mt * 16 + m0;
                int idx = row * 512 + ((((kt << 2) | q) ^ (row & 7)) << 3);
                afr[mt] = __builtin_bit_cast(bf16x8,
                    *reinterpret_cast<const s16x8*>(&xcA[idx]));
            }
            #pragma unroll
            for (int j = 0; j < 2; ++j) {
                bf16x8 bf = __builtin_bit_cast(bf16x8, Tb[cur][k2 * 2 + j]);
                #pragma unroll
                for (int mt = 0; mt < 4; ++mt)
                    gac[j][mt] = __builtin_amdgcn_mfma_f32_16x16x32_bf16(
                        afr[mt], bf, gac[j][mt], 0, 0, 0);
            }
        }
    }

    // ---- Epilogue: h_out = h + z*(tanh(g+bh) - h)
    #pragma unroll
    for (int j = 0; j < 2; ++j) {
        int col = 32 * wv + j * 16 + m0;
        #pragma unroll
        for (int mt = 0; mt < 4; ++mt) {
            #pragma unroll
            for (int rg = 0; rg < 4; ++rg) {
                int row = mt * 16 + q * 4 + rg;
                float zs = sigmoid_f(rz[2 + j][mt][rg] + bzv[j]);
                float gv = tanh_f(gac[j][mt][rg] + bhv[j]);
                float hval = rz[j][mt][rg];
                out[(size_t)(rowBase + row) * 256 + col] = hval + zs * (gv - hval);
            }
        }
    }
}

extern "C" void kernel_launch(void* const* d_in, const int* in_sizes, int n_in,
                              void* d_out, int out_size, void* d_ws, size_t ws_size,
                              hipStream_t stream) {
    const float* x   = (const float*)d_in[0];
    const float* h   = (const float*)d_in[1];
    const float* wr  = (const float*)d_in[2];
    const float* wz  = (const float*)d_in[3];
    const float* whh = (const float*)d_in[4];
    const float* whx = (const float*)d_in[5];
    const float* br  = (const float*)d_in[6];
    const float* bz  = (const float*)d_in[7];
    const float* bh  = (const float*)d_in[8];
    float* out = (float*)d_out;

    unsigned short* wrz = (unsigned short*)d_ws;       // 512 KB
    unsigned short* wg  = wrz + WRZ_ELEMS;             // 256 KB

    prep_weights<<<192, 256, 0, stream>>>(wr, wz, whh, whx, wrz, wg);
    gru_fused<<<B_TOT / MT, 512, 0, stream>>>(x, h, wrz, wg, br, bz, bh, out);
}